// Round 1
// baseline (359.768 us; speedup 1.0000x reference)
//
#include <hip/hip_runtime.h>
#include <cstdint>

#define B_SZ 8192
#define IN_SZ 1024
#define H_SZ 1024

typedef unsigned short u16;
typedef __bf16 bf16_t;
typedef bf16_t bf16x8 __attribute__((ext_vector_type(8)));
typedef float floatx4 __attribute__((ext_vector_type(4)));

__device__ __forceinline__ u16 f2bf(float f) {
    unsigned int u = __float_as_uint(f);
    u += 0x7fffu + ((u >> 16) & 1u);   // RNE
    return (u16)(u >> 16);
}

// async global->LDS, 16B per lane; LDS dest = wave-uniform base + lane*16
__device__ __forceinline__ void g2l16(const u16* g, u16* l) {
    __builtin_amdgcn_global_load_lds(
        (__attribute__((address_space(1))) void*)(uintptr_t)g,
        (__attribute__((address_space(3))) void*)(uint32_t)(uintptr_t)l,
        16, 0, 0);
}

// ---------------- fused fp32 -> bf16 conversion (one launch for all 8 tensors) ----
// blocks [0,8192): input; [8192,16384): hidden; [16384,22528): 6 weights x 1024 blocks
__global__ __launch_bounds__(256) void cvt_all(
    const float* __restrict__ x, const float* __restrict__ h,
    const float* __restrict__ w0, const float* __restrict__ w1,
    const float* __restrict__ w2, const float* __restrict__ w3,
    const float* __restrict__ w4, const float* __restrict__ w5,
    u16* __restrict__ dx, u16* __restrict__ dh,
    u16* __restrict__ dw0, u16* __restrict__ dw1, u16* __restrict__ dw2,
    u16* __restrict__ dw3, u16* __restrict__ dw4, u16* __restrict__ dw5) {
    const int b = blockIdx.x;
    const float* s;
    u16* d;
    int off;
    if (b < 8192) {
        s = x; d = dx; off = (b << 8) + threadIdx.x;
    } else if (b < 16384) {
        s = h; d = dh; off = ((b - 8192) << 8) + threadIdx.x;
    } else {
        const int wb = b - 16384;
        const int w = wb >> 10;
        off = ((wb & 1023) << 8) + threadIdx.x;
        switch (w) {
            case 0: s = w0; d = dw0; break;
            case 1: s = w1; d = dw1; break;
            case 2: s = w2; d = dw2; break;
            case 3: s = w3; d = dw3; break;
            case 4: s = w4; d = dw4; break;
            default: s = w5; d = dw5; break;
        }
    }
    float4 v = ((const float4*)s)[off];
    ushort4 o;
    o.x = f2bf(v.x); o.y = f2bf(v.y); o.z = f2bf(v.z); o.w = f2bf(v.w);
    ((ushort4*)d)[off] = o;
}

// ---------------- fused two-segment NT GEMM + gate epilogue ----------------
// C[m,n] = sum_k A0[m,k]*B0[n,k] + sum_k A1[m,k]*B1[n,k]   (K=1024 per segment)
// MODE 0 (fused r+z, N=2048): cols < 1024 -> r = sigmoid(C+bir+bhr),
//     out_rh[m,c] = bf16(r*hidden); cols >= 1024 -> out_f[m,c-1024] = sigmoid(C+biz+bhz)
// MODE 2 (h~): ht = tanh(C+bih+bhh); out_f = z*hidden + (1-z)*ht
// Double-buffered LDS, ONE barrier per K-step: stage(next) overlaps compute(cur);
// the __syncthreads vmcnt(0)+lgkmcnt(0) drain is the pipeline wait.
template <int MODE>
__global__ __launch_bounds__(256, 4) void gemm_gate(
    const u16* __restrict__ A0, const u16* __restrict__ B0,
    const u16* __restrict__ A1, const u16* __restrict__ B1,
    const float* __restrict__ bx0, const float* __restrict__ bh0,
    const float* __restrict__ bx1, const float* __restrict__ bh1,
    const float* __restrict__ hidden, const float* __restrict__ zbuf,
    u16* __restrict__ out_rh, float* __restrict__ out_f) {
    constexpr int BM = 128, BN = 128, BK = 32, K = 1024;
    __shared__ u16 As[2][BM * BK];   // 2 x 8 KB, row-major [128][32], linear (global_load_lds)
    __shared__ u16 Bs[2][BN * BK];   // 2 x 8 KB
    const int tid = threadIdx.x;
    const int wave = tid >> 6;
    const int lane = tid & 63;
    const int bn = blockIdx.x, bm = blockIdx.y;
    const int wr = wave >> 1, wc = wave & 1;   // 2x2 wave grid, 64x64 per wave

    const floatx4 z4 = {0.f, 0.f, 0.f, 0.f};
    floatx4 acc[4][4];
#pragma unroll
    for (int i = 0; i < 4; ++i)
#pragma unroll
        for (int j = 0; j < 4; ++j) acc[i][j] = z4;

    // per-thread staging constants: chunk c = j*256 + wave*64 + lane, j in {0,1}
    const int c0 = wave * 64 + lane;
    const int c1 = 256 + c0;
    const int row0 = c0 >> 2, s0 = c0 & 3;
    const int row1 = c1 >> 2, s1 = c1 & 3;
    const size_t aA0 = (size_t)(bm * BM + row0) * K + s0 * 8;
    const size_t aA1 = (size_t)(bm * BM + row1) * K + s1 * 8;
    const size_t aB0 = (size_t)(bn * BN + row0) * K + s0 * 8;
    const size_t aB1 = (size_t)(bn * BN + row1) * K + s1 * 8;
    const int ldsb0 = (wave * 64) * 8;          // wave-uniform u16 index, j=0
    const int ldsb1 = (256 + wave * 64) * 8;    // j=1

    auto stage = [&](int buf, int step) {
        const int seg = step >> 5;              // 32 K-steps per segment
        const int k0 = (step & 31) << 5;        // *BK
        const u16* __restrict__ Ag = seg ? A1 : A0;
        const u16* __restrict__ Bg = seg ? B1 : B0;
        g2l16(Ag + aA0 + k0, &As[buf][ldsb0]);
        g2l16(Bg + aB0 + k0, &Bs[buf][ldsb0]);
        g2l16(Ag + aA1 + k0, &As[buf][ldsb1]);
        g2l16(Bg + aB1 + k0, &Bs[buf][ldsb1]);
    };

    const int mr = lane & 15;
    const int q8 = (lane >> 4) * 8;
    auto compute = [&](int buf) {
        bf16x8 af[4], bfv[4];
#pragma unroll
        for (int i = 0; i < 4; ++i)
            af[i] = *(const bf16x8*)&As[buf][(wr * 64 + i * 16 + mr) * BK + q8];
#pragma unroll
        for (int j = 0; j < 4; ++j)
            bfv[j] = *(const bf16x8*)&Bs[buf][(wc * 64 + j * 16 + mr) * BK + q8];
#pragma unroll
        for (int i = 0; i < 4; ++i)
#pragma unroll
            for (int j = 0; j < 4; ++j)
                acc[i][j] = __builtin_amdgcn_mfma_f32_16x16x32_bf16(
                    af[i], bfv[j], acc[i][j], 0, 0, 0);
    };

    stage(0, 0);
    __syncthreads();                 // vmcnt(0) drain: buf0 ready
    int cur = 0;
    for (int step = 0; step < 63; ++step) {
        stage(cur ^ 1, step + 1);    // loads fly during compute(cur)
        compute(cur);
        __syncthreads();             // drains this step's stage; all reads of cur done
        cur ^= 1;
    }
    compute(cur);                    // step 63, no trailing barrier needed

    // epilogue: C/D layout col=lane&15, row=(lane>>4)*4+reg (m89/m91 verified)
    const int colBase = bn * BN + wc * 64 + (lane & 15);
    const int rowBase = bm * BM + wr * 64 + (lane >> 4) * 4;
    if constexpr (MODE == 0) {
        const bool is_r = (colBase < H_SZ);   // block-uniform: region boundary % BN == 0
#pragma unroll
        for (int j = 0; j < 4; ++j) {
            const int coln = colBase + j * 16;
            const int cb = is_r ? coln : coln - H_SZ;
            const float bias = is_r ? (bx0[cb] + bh0[cb]) : (bx1[cb] + bh1[cb]);
#pragma unroll
            for (int i = 0; i < 4; ++i) {
#pragma unroll
                for (int r = 0; r < 4; ++r) {
                    const int rown = rowBase + i * 16 + r;
                    const size_t idx = (size_t)rown * H_SZ + cb;
                    const float v = acc[i][j][r] + bias;
                    const float sg = 1.0f / (1.0f + __expf(-v));
                    if (is_r) {
                        out_rh[idx] = f2bf(sg * hidden[idx]);
                    } else {
                        out_f[idx] = sg;
                    }
                }
            }
        }
    } else {
#pragma unroll
        for (int j = 0; j < 4; ++j) {
            const int coln = colBase + j * 16;
            const float bias = bx0[coln] + bh0[coln];
#pragma unroll
            for (int i = 0; i < 4; ++i) {
#pragma unroll
                for (int r = 0; r < 4; ++r) {
                    const int rown = rowBase + i * 16 + r;
                    const size_t idx = (size_t)rown * H_SZ + coln;
                    const float v = acc[i][j][r] + bias;
                    const float ht = tanhf(v);
                    const float zz = zbuf[idx];
                    const float hh = hidden[idx];
                    out_f[idx] = zz * hh + (1.0f - zz) * ht;
                }
            }
        }
    }
}

// ---------------- row-wise log_softmax over H=1024 ----------------
__global__ __launch_bounds__(256) void lsm_kernel(const float* __restrict__ nh,
                                                  float* __restrict__ out) {
    const int row = blockIdx.x;
    const int tid = threadIdx.x;
    const int wave = tid >> 6, lane = tid & 63;
    const float4 v = ((const float4*)(nh + (size_t)row * H_SZ))[tid];
    __shared__ float redm[4];
    __shared__ float reds[4];
    float m = fmaxf(fmaxf(v.x, v.y), fmaxf(v.z, v.w));
#pragma unroll
    for (int o = 32; o; o >>= 1) m = fmaxf(m, __shfl_xor(m, o));
    if (lane == 0) redm[wave] = m;
    __syncthreads();
    const float M = fmaxf(fmaxf(redm[0], redm[1]), fmaxf(redm[2], redm[3]));
    float s = __expf(v.x - M) + __expf(v.y - M) + __expf(v.z - M) + __expf(v.w - M);
#pragma unroll
    for (int o = 32; o; o >>= 1) s += __shfl_xor(s, o);
    if (lane == 0) reds[wave] = s;
    __syncthreads();
    const float S = reds[0] + reds[1] + reds[2] + reds[3];
    const float lse = M + __logf(S);
    float4 ov;
    ov.x = v.x - lse; ov.y = v.y - lse; ov.z = v.z - lse; ov.w = v.w - lse;
    ((float4*)(out + (size_t)row * H_SZ))[tid] = ov;
}

extern "C" void kernel_launch(void* const* d_in, const int* in_sizes, int n_in,
                              void* d_out, int out_size, void* d_ws, size_t ws_size,
                              hipStream_t stream) {
    const float* input  = (const float*)d_in[0];
    const float* hidden = (const float*)d_in[1];
    const float* Wir = (const float*)d_in[2];  const float* bir = (const float*)d_in[3];
    const float* Whr = (const float*)d_in[4];  const float* bhr = (const float*)d_in[5];
    const float* Wiz = (const float*)d_in[6];  const float* biz = (const float*)d_in[7];
    const float* Whz = (const float*)d_in[8];  const float* bhz = (const float*)d_in[9];
    const float* Wih = (const float*)d_in[10]; const float* bih = (const float*)d_in[11];
    const float* Whh = (const float*)d_in[12]; const float* bhh = (const float*)d_in[13];

    // workspace layout (92 MB total)
    char* ws = (char*)d_ws;
    u16* Xb   = (u16*)(ws);                     // 16 MB  input bf16
    u16* Hb   = (u16*)(ws + (16u << 20));       // 16 MB  hidden bf16
    u16* Wrzx = (u16*)(ws + (32u << 20));       //  4 MB  concat(Wir, Wiz) [2048,1024]
    u16* Wrzh = (u16*)(ws + (36u << 20));       //  4 MB  concat(Whr, Whz) [2048,1024]
    u16* Whx  = (u16*)(ws + (40u << 20));       //  2 MB  Wih
    u16* Whhb = (u16*)(ws + (42u << 20));       //  2 MB  Whh
    u16* RHb  = (u16*)(ws + (44u << 20));       // 16 MB  r*hidden bf16
    float* Zf = (float*)(ws + (60u << 20));     // 32 MB  z f32

    float* out_lsm = (float*)d_out;
    float* out_nh  = (float*)d_out + (size_t)B_SZ * H_SZ;

    // one conversion launch: input + hidden + 6 weights (weights written into
    // concatenated r|z layouts so the r and z GEMMs fuse into one N=2048 GEMM)
    cvt_all<<<22528, 256, 0, stream>>>(
        input, hidden, Wir, Whr, Wiz, Whz, Wih, Whh,
        Xb, Hb,
        Wrzx,                       // Wir -> rows [0,1024) of rz-x
        Wrzh,                       // Whr -> rows [0,1024) of rz-h
        Wrzx + (1u << 20),          // Wiz -> rows [1024,2048)
        Wrzh + (1u << 20),          // Whz -> rows [1024,2048)
        Whx, Whhb);

    // fused r+z GEMM: N=2048, grid 16x64 = 1024 blocks (4 blocks/CU)
    gemm_gate<0><<<dim3(16, 64), 256, 0, stream>>>(
        Xb, Wrzx, Hb, Wrzh, bir, bhr, biz, bhz, hidden, nullptr, RHb, Zf);
    // h~ GEMM: N=1024, grid 8x64 = 512 blocks
    gemm_gate<2><<<dim3(8, 64), 256, 0, stream>>>(
        Xb, Whx, RHb, Whhb, bih, bhh, nullptr, nullptr, hidden, Zf, nullptr, out_nh);

    lsm_kernel<<<B_SZ, 256, 0, stream>>>(out_nh, out_lsm);
}